// Round 2
// baseline (135.390 us; speedup 1.0000x reference)
//
#include <hip/hip_runtime.h>
#include <hip/hip_bf16.h>
#include <math.h>

#define N_LOC   8192
#define C_SIZE  2048
#define A_SIZE  512
#define CTRL_IN 1024
#define D_FULL  2560   // A_SIZE + C_SIZE
#define EPS_F   1e-7f
#define NCHUNK  128    // row chunks for read_vec partials (8192/NCHUNK=64 rows/chunk)

__device__ __forceinline__ float waveReduceSum(float v) {
    #pragma unroll
    for (int off = 32; off > 0; off >>= 1) v += __shfl_xor(v, off, 64);
    return v;
}
__device__ __forceinline__ float waveReduceMax(float v) {
    #pragma unroll
    for (int off = 32; off > 0; off >>= 1) v = fmaxf(v, __shfl_xor(v, off, 64));
    return v;
}

// ---------------------------------------------------------------- K1h: h-driven mat-vecs
// waves: [0,2560) query = Wq@h + bq
//        [2560,4608) erase = We@h + be
//        [4608,6656) wh = Wch@h
// h staged in LDS; W streamed with 8 outstanding float4 loads per wave.
__global__ __launch_bounds__(512, 8) void k_matvec_h(
    const float* __restrict__ h,
    const float* __restrict__ Wq, const float* __restrict__ bq,
    const float* __restrict__ We, const float* __restrict__ be,
    const float* __restrict__ Wch,
    float* __restrict__ q_out, float* __restrict__ erase_out, float* __restrict__ wh_out)
{
    __shared__ float4 sh[2048];          // 32 KB: all of h
    int tid = threadIdx.x;
    const float4* h4 = (const float4*)h;
    #pragma unroll
    for (int k = 0; k < 4; ++k) sh[tid + 512 * k] = h4[tid + 512 * k];
    __syncthreads();

    int wave = blockIdx.x * 8 + (tid >> 6);
    int lane = tid & 63;

    const float* W; float bias; float* out;
    if (wave < 2560)      { int r = wave;        W = Wq  + (size_t)r * 8192; bias = bq[r]; out = q_out + r; }
    else if (wave < 4608) { int r = wave - 2560; W = We  + (size_t)r * 8192; bias = be[r]; out = erase_out + r; }
    else                  { int r = wave - 4608; W = Wch + (size_t)r * 8192; bias = 0.f;   out = wh_out + r; }

    const float4* W4 = (const float4*)W;
    float4 acc = make_float4(0.f, 0.f, 0.f, 0.f);
    #pragma unroll
    for (int t = 0; t < 4; ++t) {
        float4 w[8];
        #pragma unroll
        for (int u = 0; u < 8; ++u) w[u] = W4[lane + 64 * u + 512 * t];
        #pragma unroll
        for (int u = 0; u < 8; ++u) {
            float4 v = sh[lane + 64 * u + 512 * t];
            acc.x += w[u].x * v.x; acc.y += w[u].y * v.y;
            acc.z += w[u].z * v.z; acc.w += w[u].w * v.w;
        }
    }
    float s = acc.x + acc.y + acc.z + acc.w;
    s = waveReduceSum(s);
    if (lane == 0) *out = s + bias;
}

// ---------------------------------------------------------------- K1x: wx = Wci@x (2048 rows, len 1024)
__global__ void k_matvec_x(const float* __restrict__ x, const float* __restrict__ Wci,
                           float* __restrict__ wx_out)
{
    int wave = (blockIdx.x * blockDim.x + threadIdx.x) >> 6;
    int lane = threadIdx.x & 63;
    if (wave >= 2048) return;
    const float4* W4 = (const float4*)(Wci + (size_t)wave * 1024);
    const float4* x4 = (const float4*)x;
    float4 w[4];
    #pragma unroll
    for (int u = 0; u < 4; ++u) w[u] = W4[lane + 64 * u];
    float acc = 0.f;
    #pragma unroll
    for (int u = 0; u < 4; ++u) {
        float4 v = x4[lane + 64 * u];
        acc += w[u].x * v.x + w[u].y * v.y + w[u].z * v.z + w[u].w * v.w;
    }
    acc = waveReduceSum(acc);
    if (lane == 0) wx_out[wave] = acc;
}

// ---------------------------------------------------------------- K2: scalars + cdiff
// scal[0]=beta, scal[1]=gamma, scal[2]=q_norm, scal[3]=alpha
__global__ void k_scalars(const float* __restrict__ h, const float* __restrict__ x,
                          const float* __restrict__ us, const float* __restrict__ bs,
                          const float* __restrict__ ul, const float* __restrict__ bl,
                          const float* __restrict__ uca, const float* __restrict__ bca,
                          const float* __restrict__ q, const float* __restrict__ erase,
                          const float* __restrict__ wh, const float* __restrict__ wx,
                          float* __restrict__ scal, float* __restrict__ cdiff)
{
    __shared__ float red[16];
    __shared__ float sh_alpha;
    int tid = threadIdx.x, lane = tid & 63, wid = tid >> 6;

    float s_us = 0.f, s_ul = 0.f, s_a = 0.f, s_q2 = 0.f;
    for (int i = tid; i < 8192; i += 1024) {
        float hv = h[i];
        s_us += us[i] * hv;
        s_ul += ul[i] * hv;
        s_a  += uca[i] * hv;
    }
    { int i = tid; if (i < 1024) s_a += uca[8192 + i] * x[i]; }
    for (int i = tid; i < 2560; i += 1024) { float qv = q[i]; s_q2 += qv * qv; }

    float vals[4] = { s_us, s_ul, s_a, s_q2 };
    float res[4];
    #pragma unroll
    for (int k = 0; k < 4; ++k) {
        float v = waveReduceSum(vals[k]);
        __syncthreads();
        if (lane == 0) red[wid] = v;
        __syncthreads();
        float r = 0.f;
        if (tid == 0) { for (int i = 0; i < 16; ++i) r += red[i]; }
        res[k] = r;
    }

    if (tid == 0) {
        float z = res[0] + bs[0];
        float sp = (z > 20.f) ? z : log1pf(expf(z));
        float beta  = sp + 1.0f;
        float gamma = 1.f / (1.f + expf(-(res[1] + bl[0])));
        float alpha = res[2] + bca[0];
        float qn    = fmaxf(sqrtf(res[3]), EPS_F);
        scal[0] = beta; scal[1] = gamma; scal[2] = qn; scal[3] = alpha;
        sh_alpha = alpha;
    }
    __syncthreads();
    float alpha = sh_alpha;
    for (int j = tid; j < 2048; j += 1024) {
        float cand = fmaxf(wh[j] + alpha * wx[j], 0.f);
        cdiff[j] = cand - erase[j];
    }
}

// ---------------------------------------------------------------- K3: row pass (dots, norms, logits, new_ema)
__global__ void k_rowpass(const float* __restrict__ ma, const float* __restrict__ mc,
                          const float* __restrict__ q, const float* __restrict__ ema,
                          const float* __restrict__ scal,
                          float* __restrict__ logit, float* __restrict__ newema_out)
{
    int wave = (blockIdx.x * blockDim.x + threadIdx.x) >> 6;
    int lane = threadIdx.x & 63;
    if (wave >= N_LOC) return;
    int row = wave;

    const float4* a4 = (const float4*)(ma + (size_t)row * A_SIZE);
    const float4* c4 = (const float4*)(mc + (size_t)row * C_SIZE);
    const float4* q4 = (const float4*)q;

    float dot = 0.f, ssq = 0.f;
    #pragma unroll
    for (int i = lane; i < 128; i += 64) {           // address part: 512 floats
        float4 v = a4[i], qq = q4[i];
        dot += v.x*qq.x + v.y*qq.y + v.z*qq.z + v.w*qq.w;
        ssq += v.x*v.x + v.y*v.y + v.z*v.z + v.w*v.w;
    }
    #pragma unroll
    for (int i = lane; i < 512; i += 64) {           // contents part: 2048 floats
        float4 v = c4[i], qq = q4[128 + i];
        dot += v.x*qq.x + v.y*qq.y + v.z*qq.z + v.w*qq.w;
        ssq += v.x*v.x + v.y*v.y + v.z*v.z + v.w*v.w;
    }
    dot = waveReduceSum(dot);
    ssq = waveReduceSum(ssq);
    if (lane == 0) {
        float beta = scal[0], gamma = scal[1], qn = scal[2];
        float mn  = fmaxf(sqrtf(ssq), EPS_F);
        float sim = beta * dot / (mn * qn);
        float e   = ema[row];
        logit[row]      = sim - gamma * e;
        newema_out[row] = 0.1f * e + 0.9f * sim;
    }
}

// ---------------------------------------------------------------- K4: softmax over 8192 logits
__global__ void k_softmax(const float* __restrict__ logit, float* __restrict__ addr_out)
{
    __shared__ float red[16];
    __shared__ float s_max, s_sum;
    int tid = threadIdx.x, lane = tid & 63, wid = tid >> 6;

    float v[8];
    float lmax = -INFINITY;
    #pragma unroll
    for (int k = 0; k < 8; ++k) { v[k] = logit[tid + k * 1024]; lmax = fmaxf(lmax, v[k]); }
    lmax = waveReduceMax(lmax);
    if (lane == 0) red[wid] = lmax;
    __syncthreads();
    if (tid == 0) { float m = red[0]; for (int i = 1; i < 16; ++i) m = fmaxf(m, red[i]); s_max = m; }
    __syncthreads();
    float m = s_max, lsum = 0.f;
    #pragma unroll
    for (int k = 0; k < 8; ++k) { v[k] = expf(v[k] - m); lsum += v[k]; }
    lsum = waveReduceSum(lsum);
    __syncthreads();
    if (lane == 0) red[wid] = lsum;
    __syncthreads();
    if (tid == 0) { float s = 0.f; for (int i = 0; i < 16; ++i) s += red[i]; s_sum = s; }
    __syncthreads();
    float inv = 1.f / s_sum;
    #pragma unroll
    for (int k = 0; k < 8; ++k) addr_out[tid + k * 1024] = v[k] * inv;
}

// ---------------------------------------------------------------- K5: fused column pass (new_mem + read_vec partials)
// grid: (D_FULL/256, NCHUNK); each thread owns one full_mem column within one 64-row chunk
__global__ void k_colpass(const float* __restrict__ ma, const float* __restrict__ mc,
                          const float* __restrict__ addr, const float* __restrict__ cdiff,
                          float* __restrict__ newmem_out, float* __restrict__ rvpart)
{
    int c     = blockIdx.x * 256 + threadIdx.x;   // 0..2559
    int chunk = blockIdx.y;                       // 0..NCHUNK-1
    const int RPC = N_LOC / NCHUNK;               // 64
    int r0 = chunk * RPC, r1 = r0 + RPC;

    float acc = 0.f;
    if (c < A_SIZE) {
        const float* p = ma + c;
        #pragma unroll 8
        for (int r = r0; r < r1; ++r) {
            float val = p[(size_t)r * A_SIZE];
            float a = addr[r];
            if (r != N_LOC - 1) acc += a * val;
        }
    } else {
        int cc = c - A_SIZE;
        float cd = cdiff[cc];
        const float* p = mc + cc;
        float* o = newmem_out + cc;
        #pragma unroll 8
        for (int r = r0; r < r1; ++r) {
            float val = p[(size_t)r * C_SIZE];
            float a = addr[r];
            if (r != N_LOC - 1) acc += a * val;
            o[(size_t)r * C_SIZE] = val + a * cd;
        }
    }
    rvpart[(size_t)chunk * D_FULL + c] = acc;
}

// ---------------------------------------------------------------- K6: reduce read_vec partials
__global__ void k_rvreduce(const float* __restrict__ rvpart, float* __restrict__ rv_out)
{
    int c = blockIdx.x * 256 + threadIdx.x;
    if (c >= D_FULL) return;
    float s = 0.f;
    #pragma unroll 8
    for (int k = 0; k < NCHUNK; ++k) s += rvpart[(size_t)k * D_FULL + c];
    rv_out[c] = s;
}

// ---------------------------------------------------------------- launch
extern "C" void kernel_launch(void* const* d_in, const int* in_sizes, int n_in,
                              void* d_out, int out_size, void* d_ws, size_t ws_size,
                              hipStream_t stream)
{
    const float* h   = (const float*)d_in[0];
    const float* x   = (const float*)d_in[1];
    const float* mc  = (const float*)d_in[2];
    const float* ma  = (const float*)d_in[3];
    const float* ema = (const float*)d_in[4];
    const float* Wq  = (const float*)d_in[5];
    const float* bq  = (const float*)d_in[6];
    const float* us  = (const float*)d_in[7];
    const float* bs  = (const float*)d_in[8];
    const float* ul  = (const float*)d_in[9];
    const float* bl  = (const float*)d_in[10];
    const float* We  = (const float*)d_in[11];
    const float* be  = (const float*)d_in[12];
    const float* Wch = (const float*)d_in[13];
    const float* Wci = (const float*)d_in[14];
    const float* uca = (const float*)d_in[15];
    const float* bca = (const float*)d_in[16];

    float* out = (float*)d_out;
    float* rv_out     = out;                              // 2560
    float* newmem_out = out + D_FULL;                     // 8192*2048
    float* addr_out   = newmem_out + (size_t)N_LOC * C_SIZE; // 8192
    float* newema_out = addr_out + N_LOC;                 // 8192

    float* ws = (float*)d_ws;
    float* w_query = ws;            // 2560
    float* w_erase = ws + 2560;     // 2048
    float* w_wh    = ws + 4608;     // 2048
    float* w_wx    = ws + 6656;     // 2048
    float* w_cdiff = ws + 8704;     // 2048
    float* w_scal  = ws + 10752;    // 8
    float* w_logit = ws + 10760;    // 8192
    float* w_rvp   = ws + 18952;    // NCHUNK*2560

    // K1h: h-driven mat-vecs (6656 waves, 8 waves/block, h in LDS)
    k_matvec_h<<<832, 512, 0, stream>>>(h, Wq, bq, We, be, Wch,
                                        w_query, w_erase, w_wh);
    // K1x: wx = Wci@x
    k_matvec_x<<<512, 256, 0, stream>>>(x, Wci, w_wx);
    // K2: scalars + cdiff
    k_scalars<<<1, 1024, 0, stream>>>(h, x, us, bs, ul, bl, uca, bca,
                                      w_query, w_erase, w_wh, w_wx, w_scal, w_cdiff);
    // K3: per-row dot/norm -> logit, new_ema
    k_rowpass<<<2048, 256, 0, stream>>>(ma, mc, w_query, ema, w_scal, w_logit, newema_out);
    // K4: softmax -> address
    k_softmax<<<1, 1024, 0, stream>>>(w_logit, addr_out);
    // K5: fused new_mem + read_vec partials
    dim3 g5(D_FULL / 256, NCHUNK);
    k_colpass<<<g5, 256, 0, stream>>>(ma, mc, addr_out, w_cdiff, newmem_out, w_rvp);
    // K6: reduce read_vec partials
    k_rvreduce<<<10, 256, 0, stream>>>(w_rvp, rv_out);
}

// Round 3
// 112.251 us; speedup vs baseline: 1.2061x; 1.2061x over previous
//
#include <hip/hip_runtime.h>
#include <hip/hip_bf16.h>
#include <math.h>

#define N_LOC   8192
#define C_SIZE  2048
#define A_SIZE  512
#define CTRL_IN 1024
#define D_FULL  2560   // A_SIZE + C_SIZE
#define EPS_F   1e-7f
#define NCHUNK  128    // row chunks for read_vec partials (8192/NCHUNK=64 rows/chunk)

__device__ __forceinline__ float waveReduceSum(float v) {
    #pragma unroll
    for (int off = 32; off > 0; off >>= 1) v += __shfl_xor(v, off, 64);
    return v;
}
__device__ __forceinline__ float waveReduceMax(float v) {
    #pragma unroll
    for (int off = 32; off > 0; off >>= 1) v = fmaxf(v, __shfl_xor(v, off, 64));
    return v;
}

// ---------------------------------------------------------------- K1: all mat-vecs, one kernel
// blocks [0,1664): h-driven rows (4 waves/block, h staged in LDS)
//   wave 0..2559   -> query = Wq@h + bq
//   wave 2560..4607-> erase = We@h + be
//   wave 4608..6655-> wh    = Wch@h
// blocks [1664,2176): x-driven rows, wave -> wx = Wci@x (len 1024), x via L2
// Double-buffered 8x float4 load batches: ~8-16 KB in flight per wave.
#define HBLK 1664
__global__ __launch_bounds__(256) void k_matvec(
    const float* __restrict__ h, const float* __restrict__ x,
    const float* __restrict__ Wq, const float* __restrict__ bq,
    const float* __restrict__ We, const float* __restrict__ be,
    const float* __restrict__ Wch, const float* __restrict__ Wci,
    float* __restrict__ q_out, float* __restrict__ erase_out,
    float* __restrict__ wh_out, float* __restrict__ wx_out)
{
    __shared__ float4 sh[2048];          // 32 KB: all of h
    int tid  = threadIdx.x;
    int lane = tid & 63;
    int wv   = tid >> 6;
    int blk  = blockIdx.x;

    if (blk < HBLK) {
        const float4* h4 = (const float4*)h;
        #pragma unroll
        for (int k = 0; k < 8; ++k) sh[tid + 256 * k] = h4[tid + 256 * k];
        __syncthreads();

        int wave = blk * 4 + wv;         // 0..6655
        const float* W; float bias; float* out;
        if (wave < 2560)      { int r = wave;        W = Wq  + (size_t)r * 8192; bias = bq[r]; out = q_out + r; }
        else if (wave < 4608) { int r = wave - 2560; W = We  + (size_t)r * 8192; bias = be[r]; out = erase_out + r; }
        else                  { int r = wave - 4608; W = Wch + (size_t)r * 8192; bias = 0.f;   out = wh_out + r; }

        const float4* W4 = (const float4*)W;
        float4 wa[8], wb[8];
        #pragma unroll
        for (int u = 0; u < 8; ++u) wa[u] = W4[lane + 64 * u];

        float acc = 0.f;
        #pragma unroll
        for (int t = 0; t < 3; ++t) {
            #pragma unroll
            for (int u = 0; u < 8; ++u) wb[u] = W4[lane + 64 * u + 512 * (t + 1)];
            #pragma unroll
            for (int u = 0; u < 8; ++u) {
                float4 v = sh[lane + 64 * u + 512 * t];
                acc += wa[u].x * v.x + wa[u].y * v.y + wa[u].z * v.z + wa[u].w * v.w;
            }
            #pragma unroll
            for (int u = 0; u < 8; ++u) wa[u] = wb[u];
        }
        #pragma unroll
        for (int u = 0; u < 8; ++u) {
            float4 v = sh[lane + 64 * u + 512 * 3];
            acc += wa[u].x * v.x + wa[u].y * v.y + wa[u].z * v.z + wa[u].w * v.w;
        }
        acc = waveReduceSum(acc);
        if (lane == 0) *out = acc + bias;
    } else {
        int row = (blk - HBLK) * 4 + wv; // 0..2047
        const float4* W4 = (const float4*)(Wci + (size_t)row * 1024);
        const float4* x4 = (const float4*)x;
        float4 w[4];
        #pragma unroll
        for (int u = 0; u < 4; ++u) w[u] = W4[lane + 64 * u];
        float acc = 0.f;
        #pragma unroll
        for (int u = 0; u < 4; ++u) {
            float4 v = x4[lane + 64 * u];
            acc += w[u].x * v.x + w[u].y * v.y + w[u].z * v.z + w[u].w * v.w;
        }
        acc = waveReduceSum(acc);
        if (lane == 0) wx_out[row] = acc;
    }
}

// ---------------------------------------------------------------- K2: scalars + cdiff
// scal[0]=beta, scal[1]=gamma, scal[2]=q_norm, scal[3]=alpha
__global__ void k_scalars(const float* __restrict__ h, const float* __restrict__ x,
                          const float* __restrict__ us, const float* __restrict__ bs,
                          const float* __restrict__ ul, const float* __restrict__ bl,
                          const float* __restrict__ uca, const float* __restrict__ bca,
                          const float* __restrict__ q, const float* __restrict__ erase,
                          const float* __restrict__ wh, const float* __restrict__ wx,
                          float* __restrict__ scal, float* __restrict__ cdiff)
{
    __shared__ float red[16];
    __shared__ float sh_alpha;
    int tid = threadIdx.x, lane = tid & 63, wid = tid >> 6;

    float s_us = 0.f, s_ul = 0.f, s_a = 0.f, s_q2 = 0.f;
    for (int i = tid; i < 8192; i += 1024) {
        float hv = h[i];
        s_us += us[i] * hv;
        s_ul += ul[i] * hv;
        s_a  += uca[i] * hv;
    }
    { int i = tid; if (i < 1024) s_a += uca[8192 + i] * x[i]; }
    for (int i = tid; i < 2560; i += 1024) { float qv = q[i]; s_q2 += qv * qv; }

    float vals[4] = { s_us, s_ul, s_a, s_q2 };
    float res[4];
    #pragma unroll
    for (int k = 0; k < 4; ++k) {
        float v = waveReduceSum(vals[k]);
        __syncthreads();
        if (lane == 0) red[wid] = v;
        __syncthreads();
        float r = 0.f;
        if (tid == 0) { for (int i = 0; i < 16; ++i) r += red[i]; }
        res[k] = r;
    }

    if (tid == 0) {
        float z = res[0] + bs[0];
        float sp = (z > 20.f) ? z : log1pf(expf(z));
        float beta  = sp + 1.0f;
        float gamma = 1.f / (1.f + expf(-(res[1] + bl[0])));
        float alpha = res[2] + bca[0];
        float qn    = fmaxf(sqrtf(res[3]), EPS_F);
        scal[0] = beta; scal[1] = gamma; scal[2] = qn; scal[3] = alpha;
        sh_alpha = alpha;
    }
    __syncthreads();
    float alpha = sh_alpha;
    for (int j = tid; j < 2048; j += 1024) {
        float cand = fmaxf(wh[j] + alpha * wx[j], 0.f);
        cdiff[j] = cand - erase[j];
    }
}

// ---------------------------------------------------------------- K3: row pass (dots, norms, logits, new_ema)
__global__ void k_rowpass(const float* __restrict__ ma, const float* __restrict__ mc,
                          const float* __restrict__ q, const float* __restrict__ ema,
                          const float* __restrict__ scal,
                          float* __restrict__ logit, float* __restrict__ newema_out)
{
    int wave = (blockIdx.x * blockDim.x + threadIdx.x) >> 6;
    int lane = threadIdx.x & 63;
    if (wave >= N_LOC) return;
    int row = wave;

    const float4* a4 = (const float4*)(ma + (size_t)row * A_SIZE);
    const float4* c4 = (const float4*)(mc + (size_t)row * C_SIZE);
    const float4* q4 = (const float4*)q;

    float dot = 0.f, ssq = 0.f;
    #pragma unroll
    for (int i = lane; i < 128; i += 64) {           // address part: 512 floats
        float4 v = a4[i], qq = q4[i];
        dot += v.x*qq.x + v.y*qq.y + v.z*qq.z + v.w*qq.w;
        ssq += v.x*v.x + v.y*v.y + v.z*v.z + v.w*v.w;
    }
    #pragma unroll
    for (int i = lane; i < 512; i += 64) {           // contents part: 2048 floats
        float4 v = c4[i], qq = q4[128 + i];
        dot += v.x*qq.x + v.y*qq.y + v.z*qq.z + v.w*qq.w;
        ssq += v.x*v.x + v.y*v.y + v.z*v.z + v.w*v.w;
    }
    dot = waveReduceSum(dot);
    ssq = waveReduceSum(ssq);
    if (lane == 0) {
        float beta = scal[0], gamma = scal[1], qn = scal[2];
        float mn  = fmaxf(sqrtf(ssq), EPS_F);
        float sim = beta * dot / (mn * qn);
        float e   = ema[row];
        logit[row]      = sim - gamma * e;
        newema_out[row] = 0.1f * e + 0.9f * sim;
    }
}

// ---------------------------------------------------------------- K4: softmax over 8192 logits
__global__ void k_softmax(const float* __restrict__ logit, float* __restrict__ addr_out)
{
    __shared__ float red[16];
    __shared__ float s_max, s_sum;
    int tid = threadIdx.x, lane = tid & 63, wid = tid >> 6;

    float v[8];
    float lmax = -INFINITY;
    #pragma unroll
    for (int k = 0; k < 8; ++k) { v[k] = logit[tid + k * 1024]; lmax = fmaxf(lmax, v[k]); }
    lmax = waveReduceMax(lmax);
    if (lane == 0) red[wid] = lmax;
    __syncthreads();
    if (tid == 0) { float m = red[0]; for (int i = 1; i < 16; ++i) m = fmaxf(m, red[i]); s_max = m; }
    __syncthreads();
    float m = s_max, lsum = 0.f;
    #pragma unroll
    for (int k = 0; k < 8; ++k) { v[k] = expf(v[k] - m); lsum += v[k]; }
    lsum = waveReduceSum(lsum);
    __syncthreads();
    if (lane == 0) red[wid] = lsum;
    __syncthreads();
    if (tid == 0) { float s = 0.f; for (int i = 0; i < 16; ++i) s += red[i]; s_sum = s; }
    __syncthreads();
    float inv = 1.f / s_sum;
    #pragma unroll
    for (int k = 0; k < 8; ++k) addr_out[tid + k * 1024] = v[k] * inv;
}

// ---------------------------------------------------------------- K5: fused column pass (new_mem + read_vec partials)
// grid: (D_FULL/256, NCHUNK); each thread owns one full_mem column within one 64-row chunk
__global__ void k_colpass(const float* __restrict__ ma, const float* __restrict__ mc,
                          const float* __restrict__ addr, const float* __restrict__ cdiff,
                          float* __restrict__ newmem_out, float* __restrict__ rvpart)
{
    int c     = blockIdx.x * 256 + threadIdx.x;   // 0..2559
    int chunk = blockIdx.y;                       // 0..NCHUNK-1
    const int RPC = N_LOC / NCHUNK;               // 64
    int r0 = chunk * RPC, r1 = r0 + RPC;

    float acc = 0.f;
    if (c < A_SIZE) {
        const float* p = ma + c;
        for (int r = r0; r < r1; ++r) {
            float val = p[(size_t)r * A_SIZE];
            float a = addr[r];
            if (r != N_LOC - 1) acc += a * val;
        }
    } else {
        int cc = c - A_SIZE;
        float cd = cdiff[cc];
        const float* p = mc + cc;
        float* o = newmem_out + cc;
        for (int r = r0; r < r1; ++r) {
            float val = p[(size_t)r * C_SIZE];
            float a = addr[r];
            if (r != N_LOC - 1) acc += a * val;
            o[(size_t)r * C_SIZE] = val + a * cd;
        }
    }
    rvpart[(size_t)chunk * D_FULL + c] = acc;
}

// ---------------------------------------------------------------- K6: reduce read_vec partials
__global__ void k_rvreduce(const float* __restrict__ rvpart, float* __restrict__ rv_out)
{
    int c = blockIdx.x * 256 + threadIdx.x;
    if (c >= D_FULL) return;
    float s = 0.f;
    for (int k = 0; k < NCHUNK; ++k) s += rvpart[(size_t)k * D_FULL + c];
    rv_out[c] = s;
}

// ---------------------------------------------------------------- launch
extern "C" void kernel_launch(void* const* d_in, const int* in_sizes, int n_in,
                              void* d_out, int out_size, void* d_ws, size_t ws_size,
                              hipStream_t stream)
{
    const float* h   = (const float*)d_in[0];
    const float* x   = (const float*)d_in[1];
    const float* mc  = (const float*)d_in[2];
    const float* ma  = (const float*)d_in[3];
    const float* ema = (const float*)d_in[4];
    const float* Wq  = (const float*)d_in[5];
    const float* bq  = (const float*)d_in[6];
    const float* us  = (const float*)d_in[7];
    const float* bs  = (const float*)d_in[8];
    const float* ul  = (const float*)d_in[9];
    const float* bl  = (const float*)d_in[10];
    const float* We  = (const float*)d_in[11];
    const float* be  = (const float*)d_in[12];
    const float* Wch = (const float*)d_in[13];
    const float* Wci = (const float*)d_in[14];
    const float* uca = (const float*)d_in[15];
    const float* bca = (const float*)d_in[16];

    float* out = (float*)d_out;
    float* rv_out     = out;                              // 2560
    float* newmem_out = out + D_FULL;                     // 8192*2048
    float* addr_out   = newmem_out + (size_t)N_LOC * C_SIZE; // 8192
    float* newema_out = addr_out + N_LOC;                 // 8192

    float* ws = (float*)d_ws;
    float* w_query = ws;            // 2560
    float* w_erase = ws + 2560;     // 2048
    float* w_wh    = ws + 4608;     // 2048
    float* w_wx    = ws + 6656;     // 2048
    float* w_cdiff = ws + 8704;     // 2048
    float* w_scal  = ws + 10752;    // 8
    float* w_logit = ws + 10760;    // 8192
    float* w_rvp   = ws + 18952;    // NCHUNK*2560

    // K1: all mat-vecs (1664 h-blocks + 512 x-blocks, 4 waves/block)
    k_matvec<<<2176, 256, 0, stream>>>(h, x, Wq, bq, We, be, Wch, Wci,
                                       w_query, w_erase, w_wh, w_wx);
    // K2: scalars + cdiff
    k_scalars<<<1, 1024, 0, stream>>>(h, x, us, bs, ul, bl, uca, bca,
                                      w_query, w_erase, w_wh, w_wx, w_scal, w_cdiff);
    // K3: per-row dot/norm -> logit, new_ema
    k_rowpass<<<2048, 256, 0, stream>>>(ma, mc, w_query, ema, w_scal, w_logit, newema_out);
    // K4: softmax -> address
    k_softmax<<<1, 1024, 0, stream>>>(w_logit, addr_out);
    // K5: fused new_mem + read_vec partials
    dim3 g5(D_FULL / 256, NCHUNK);
    k_colpass<<<g5, 256, 0, stream>>>(ma, mc, addr_out, w_cdiff, newmem_out, w_rvp);
    // K6: reduce read_vec partials
    k_rvreduce<<<10, 256, 0, stream>>>(w_rvp, rv_out);
}

// Round 4
// 111.940 us; speedup vs baseline: 1.2095x; 1.0028x over previous
//
#include <hip/hip_runtime.h>
#include <hip/hip_bf16.h>
#include <math.h>

#define N_LOC   8192
#define C_SIZE  2048
#define A_SIZE  512
#define CTRL_IN 1024
#define D_FULL  2560   // A_SIZE + C_SIZE
#define EPS_F   1e-7f
#define NCHUNK  128    // row chunks for read_vec partials (8192/NCHUNK=64 rows/chunk)

__device__ __forceinline__ float waveReduceSum(float v) {
    #pragma unroll
    for (int off = 32; off > 0; off >>= 1) v += __shfl_xor(v, off, 64);
    return v;
}
__device__ __forceinline__ float waveReduceMax(float v) {
    #pragma unroll
    for (int off = 32; off > 0; off >>= 1) v = fmaxf(v, __shfl_xor(v, off, 64));
    return v;
}

// ---------------------------------------------------------------- K1: all mat-vecs, block-per-row
// blocks [0,6656): h-driven rows (8192-long dot), 256 threads, 8 W-float4 + 8 h-float4 per thread,
//                  ALL loads independent -> one vmcnt drain per row, then block reduce.
//   blk 0..2559    -> query = Wq@h + bq
//   blk 2560..4607 -> erase = We@h + be
//   blk 4608..6655 -> wh    = Wch@h
// blocks [6656,8704): x-driven rows (1024-long dot), 1 W-float4 + 1 x-float4 per thread.
__global__ __launch_bounds__(256) void k_matvec(
    const float* __restrict__ h, const float* __restrict__ x,
    const float* __restrict__ Wq, const float* __restrict__ bq,
    const float* __restrict__ We, const float* __restrict__ be,
    const float* __restrict__ Wch, const float* __restrict__ Wci,
    float* __restrict__ q_out, float* __restrict__ erase_out,
    float* __restrict__ wh_out, float* __restrict__ wx_out)
{
    __shared__ float red[4];
    int tid  = threadIdx.x;
    int lane = tid & 63;
    int wid  = tid >> 6;
    int blk  = blockIdx.x;

    float acc;
    float bias = 0.f;
    float* out;

    if (blk < 6656) {
        const float* W;
        if (blk < 2560)      { int r = blk;        W = Wq  + (size_t)r * 8192; bias = bq[r]; out = q_out + r; }
        else if (blk < 4608) { int r = blk - 2560; W = We  + (size_t)r * 8192; bias = be[r]; out = erase_out + r; }
        else                 { int r = blk - 4608; W = Wch + (size_t)r * 8192; out = wh_out + r; }

        const float4* W4 = (const float4*)W;
        const float4* h4 = (const float4*)h;
        float4 w[8], v[8];
        #pragma unroll
        for (int u = 0; u < 8; ++u) w[u] = W4[tid + 256 * u];
        #pragma unroll
        for (int u = 0; u < 8; ++u) v[u] = h4[tid + 256 * u];
        acc = 0.f;
        #pragma unroll
        for (int u = 0; u < 8; ++u)
            acc += w[u].x * v[u].x + w[u].y * v[u].y + w[u].z * v[u].z + w[u].w * v[u].w;
    } else {
        int r = blk - 6656;              // 0..2047
        const float4* W4 = (const float4*)(Wci + (size_t)r * 1024);
        const float4* x4 = (const float4*)x;
        float4 w = W4[tid];
        float4 v = x4[tid];
        acc = w.x * v.x + w.y * v.y + w.z * v.z + w.w * v.w;
        out = wx_out + r;
    }

    acc = waveReduceSum(acc);
    if (lane == 0) red[wid] = acc;
    __syncthreads();
    if (tid == 0) *out = red[0] + red[1] + red[2] + red[3] + bias;
}

// ---------------------------------------------------------------- K2: scalars + cdiff
// scal[0]=beta, scal[1]=gamma, scal[2]=q_norm, scal[3]=alpha
__global__ void k_scalars(const float* __restrict__ h, const float* __restrict__ x,
                          const float* __restrict__ us, const float* __restrict__ bs,
                          const float* __restrict__ ul, const float* __restrict__ bl,
                          const float* __restrict__ uca, const float* __restrict__ bca,
                          const float* __restrict__ q, const float* __restrict__ erase,
                          const float* __restrict__ wh, const float* __restrict__ wx,
                          float* __restrict__ scal, float* __restrict__ cdiff)
{
    __shared__ float red[16];
    __shared__ float sh_alpha;
    int tid = threadIdx.x, lane = tid & 63, wid = tid >> 6;

    float s_us = 0.f, s_ul = 0.f, s_a = 0.f, s_q2 = 0.f;
    for (int i = tid; i < 8192; i += 1024) {
        float hv = h[i];
        s_us += us[i] * hv;
        s_ul += ul[i] * hv;
        s_a  += uca[i] * hv;
    }
    { int i = tid; if (i < 1024) s_a += uca[8192 + i] * x[i]; }
    for (int i = tid; i < 2560; i += 1024) { float qv = q[i]; s_q2 += qv * qv; }

    float vals[4] = { s_us, s_ul, s_a, s_q2 };
    float res[4];
    #pragma unroll
    for (int k = 0; k < 4; ++k) {
        float v = waveReduceSum(vals[k]);
        __syncthreads();
        if (lane == 0) red[wid] = v;
        __syncthreads();
        float r = 0.f;
        if (tid == 0) { for (int i = 0; i < 16; ++i) r += red[i]; }
        res[k] = r;
    }

    if (tid == 0) {
        float z = res[0] + bs[0];
        float sp = (z > 20.f) ? z : log1pf(expf(z));
        float beta  = sp + 1.0f;
        float gamma = 1.f / (1.f + expf(-(res[1] + bl[0])));
        float alpha = res[2] + bca[0];
        float qn    = fmaxf(sqrtf(res[3]), EPS_F);
        scal[0] = beta; scal[1] = gamma; scal[2] = qn; scal[3] = alpha;
        sh_alpha = alpha;
    }
    __syncthreads();
    float alpha = sh_alpha;
    for (int j = tid; j < 2048; j += 1024) {
        float cand = fmaxf(wh[j] + alpha * wx[j], 0.f);
        cdiff[j] = cand - erase[j];
    }
}

// ---------------------------------------------------------------- K3: row pass (dots, norms, logits, new_ema)
__global__ void k_rowpass(const float* __restrict__ ma, const float* __restrict__ mc,
                          const float* __restrict__ q, const float* __restrict__ ema,
                          const float* __restrict__ scal,
                          float* __restrict__ logit, float* __restrict__ newema_out)
{
    int wave = (blockIdx.x * blockDim.x + threadIdx.x) >> 6;
    int lane = threadIdx.x & 63;
    if (wave >= N_LOC) return;
    int row = wave;

    const float4* a4 = (const float4*)(ma + (size_t)row * A_SIZE);
    const float4* c4 = (const float4*)(mc + (size_t)row * C_SIZE);
    const float4* q4 = (const float4*)q;

    float dot = 0.f, ssq = 0.f;
    #pragma unroll
    for (int i = lane; i < 128; i += 64) {           // address part: 512 floats
        float4 v = a4[i], qq = q4[i];
        dot += v.x*qq.x + v.y*qq.y + v.z*qq.z + v.w*qq.w;
        ssq += v.x*v.x + v.y*v.y + v.z*v.z + v.w*v.w;
    }
    #pragma unroll
    for (int i = lane; i < 512; i += 64) {           // contents part: 2048 floats
        float4 v = c4[i], qq = q4[128 + i];
        dot += v.x*qq.x + v.y*qq.y + v.z*qq.z + v.w*qq.w;
        ssq += v.x*v.x + v.y*v.y + v.z*v.z + v.w*v.w;
    }
    dot = waveReduceSum(dot);
    ssq = waveReduceSum(ssq);
    if (lane == 0) {
        float beta = scal[0], gamma = scal[1], qn = scal[2];
        float mn  = fmaxf(sqrtf(ssq), EPS_F);
        float sim = beta * dot / (mn * qn);
        float e   = ema[row];
        logit[row]      = sim - gamma * e;
        newema_out[row] = 0.1f * e + 0.9f * sim;
    }
}

// ---------------------------------------------------------------- K4: softmax over 8192 logits
__global__ void k_softmax(const float* __restrict__ logit, float* __restrict__ addr_out)
{
    __shared__ float red[16];
    __shared__ float s_max, s_sum;
    int tid = threadIdx.x, lane = tid & 63, wid = tid >> 6;

    float v[8];
    float lmax = -INFINITY;
    #pragma unroll
    for (int k = 0; k < 8; ++k) { v[k] = logit[tid + k * 1024]; lmax = fmaxf(lmax, v[k]); }
    lmax = waveReduceMax(lmax);
    if (lane == 0) red[wid] = lmax;
    __syncthreads();
    if (tid == 0) { float m = red[0]; for (int i = 1; i < 16; ++i) m = fmaxf(m, red[i]); s_max = m; }
    __syncthreads();
    float m = s_max, lsum = 0.f;
    #pragma unroll
    for (int k = 0; k < 8; ++k) { v[k] = expf(v[k] - m); lsum += v[k]; }
    lsum = waveReduceSum(lsum);
    __syncthreads();
    if (lane == 0) red[wid] = lsum;
    __syncthreads();
    if (tid == 0) { float s = 0.f; for (int i = 0; i < 16; ++i) s += red[i]; s_sum = s; }
    __syncthreads();
    float inv = 1.f / s_sum;
    #pragma unroll
    for (int k = 0; k < 8; ++k) addr_out[tid + k * 1024] = v[k] * inv;
}

// ---------------------------------------------------------------- K5: fused column pass (new_mem + read_vec partials)
// grid: (D_FULL/256, NCHUNK); each thread owns one full_mem column within one 64-row chunk
__global__ void k_colpass(const float* __restrict__ ma, const float* __restrict__ mc,
                          const float* __restrict__ addr, const float* __restrict__ cdiff,
                          float* __restrict__ newmem_out, float* __restrict__ rvpart)
{
    int c     = blockIdx.x * 256 + threadIdx.x;   // 0..2559
    int chunk = blockIdx.y;                       // 0..NCHUNK-1
    const int RPC = N_LOC / NCHUNK;               // 64
    int r0 = chunk * RPC, r1 = r0 + RPC;

    float acc = 0.f;
    if (c < A_SIZE) {
        const float* p = ma + c;
        for (int r = r0; r < r1; ++r) {
            float val = p[(size_t)r * A_SIZE];
            float a = addr[r];
            if (r != N_LOC - 1) acc += a * val;
        }
    } else {
        int cc = c - A_SIZE;
        float cd = cdiff[cc];
        const float* p = mc + cc;
        float* o = newmem_out + cc;
        for (int r = r0; r < r1; ++r) {
            float val = p[(size_t)r * C_SIZE];
            float a = addr[r];
            if (r != N_LOC - 1) acc += a * val;
            o[(size_t)r * C_SIZE] = val + a * cd;
        }
    }
    rvpart[(size_t)chunk * D_FULL + c] = acc;
}

// ---------------------------------------------------------------- K6: reduce read_vec partials
__global__ void k_rvreduce(const float* __restrict__ rvpart, float* __restrict__ rv_out)
{
    int c = blockIdx.x * 256 + threadIdx.x;
    if (c >= D_FULL) return;
    float s = 0.f;
    for (int k = 0; k < NCHUNK; ++k) s += rvpart[(size_t)k * D_FULL + c];
    rv_out[c] = s;
}

// ---------------------------------------------------------------- launch
extern "C" void kernel_launch(void* const* d_in, const int* in_sizes, int n_in,
                              void* d_out, int out_size, void* d_ws, size_t ws_size,
                              hipStream_t stream)
{
    const float* h   = (const float*)d_in[0];
    const float* x   = (const float*)d_in[1];
    const float* mc  = (const float*)d_in[2];
    const float* ma  = (const float*)d_in[3];
    const float* ema = (const float*)d_in[4];
    const float* Wq  = (const float*)d_in[5];
    const float* bq  = (const float*)d_in[6];
    const float* us  = (const float*)d_in[7];
    const float* bs  = (const float*)d_in[8];
    const float* ul  = (const float*)d_in[9];
    const float* bl  = (const float*)d_in[10];
    const float* We  = (const float*)d_in[11];
    const float* be  = (const float*)d_in[12];
    const float* Wch = (const float*)d_in[13];
    const float* Wci = (const float*)d_in[14];
    const float* uca = (const float*)d_in[15];
    const float* bca = (const float*)d_in[16];

    float* out = (float*)d_out;
    float* rv_out     = out;                              // 2560
    float* newmem_out = out + D_FULL;                     // 8192*2048
    float* addr_out   = newmem_out + (size_t)N_LOC * C_SIZE; // 8192
    float* newema_out = addr_out + N_LOC;                 // 8192

    float* ws = (float*)d_ws;
    float* w_query = ws;            // 2560
    float* w_erase = ws + 2560;     // 2048
    float* w_wh    = ws + 4608;     // 2048
    float* w_wx    = ws + 6656;     // 2048
    float* w_cdiff = ws + 8704;     // 2048
    float* w_scal  = ws + 10752;    // 8
    float* w_logit = ws + 10760;    // 8192
    float* w_rvp   = ws + 18952;    // NCHUNK*2560

    // K1: all mat-vecs, block-per-row (6656 h-rows + 2048 x-rows)
    k_matvec<<<8704, 256, 0, stream>>>(h, x, Wq, bq, We, be, Wch, Wci,
                                       w_query, w_erase, w_wh, w_wx);
    // K2: scalars + cdiff
    k_scalars<<<1, 1024, 0, stream>>>(h, x, us, bs, ul, bl, uca, bca,
                                      w_query, w_erase, w_wh, w_wx, w_scal, w_cdiff);
    // K3: per-row dot/norm -> logit, new_ema
    k_rowpass<<<2048, 256, 0, stream>>>(ma, mc, w_query, ema, w_scal, w_logit, newema_out);
    // K4: softmax -> address
    k_softmax<<<1, 1024, 0, stream>>>(w_logit, addr_out);
    // K5: fused new_mem + read_vec partials
    dim3 g5(D_FULL / 256, NCHUNK);
    k_colpass<<<g5, 256, 0, stream>>>(ma, mc, addr_out, w_cdiff, newmem_out, w_rvp);
    // K6: reduce read_vec partials
    k_rvreduce<<<10, 256, 0, stream>>>(w_rvp, rv_out);
}

// Round 5
// 111.515 us; speedup vs baseline: 1.2141x; 1.0038x over previous
//
#include <hip/hip_runtime.h>
#include <hip/hip_bf16.h>
#include <math.h>

#define N_LOC   8192
#define C_SIZE  2048
#define A_SIZE  512
#define CTRL_IN 1024
#define D_FULL  2560   // A_SIZE + C_SIZE
#define EPS_F   1e-7f
#define NCHUNK  128    // row chunks for read_vec partials (8192/NCHUNK=64 rows/chunk)

__device__ __forceinline__ float waveReduceSum(float v) {
    #pragma unroll
    for (int off = 32; off > 0; off >>= 1) v += __shfl_xor(v, off, 64);
    return v;
}
__device__ __forceinline__ float waveReduceMax(float v) {
    #pragma unroll
    for (int off = 32; off > 0; off >>= 1) v = fmaxf(v, __shfl_xor(v, off, 64));
    return v;
}

// ---------------------------------------------------------------- K1: all mat-vecs
// h-blocks [0,1664): 512 threads, 4 rows/block, 2 waves per row (half-row each).
//   h staged ONCE per block in LDS (cuts h re-read 213->53 MB);
//   each wave: 16 INDEPENDENT float4 W-loads (issued before any LDS use) -> one drain.
//   row r: r<2560 query=Wq@h+bq | r<4608 erase=We@h+be | else wh=Wch@h
// x-blocks [1664,1920): 8 x-rows/block (wave-per-row), wx = Wci@x, x staged in LDS.
#define HBLK 1664
__device__ __forceinline__ void row_target(
    int r,
    const float* __restrict__ Wq, const float* __restrict__ bq,
    const float* __restrict__ We, const float* __restrict__ be,
    const float* __restrict__ Wch,
    float* __restrict__ q_out, float* __restrict__ erase_out, float* __restrict__ wh_out,
    const float*& W, float& bias, float*& out)
{
    if (r < 2560)      { W = Wq  + (size_t)r * 8192;            bias = bq[r]; out = q_out + r; }
    else if (r < 4608) { W = We  + (size_t)(r - 2560) * 8192;   bias = be[r - 2560]; out = erase_out + (r - 2560); }
    else               { W = Wch + (size_t)(r - 4608) * 8192;   bias = 0.f;   out = wh_out + (r - 4608); }
}

__global__ __launch_bounds__(512) void k_matvec(
    const float* __restrict__ h, const float* __restrict__ x,
    const float* __restrict__ Wq, const float* __restrict__ bq,
    const float* __restrict__ We, const float* __restrict__ be,
    const float* __restrict__ Wch, const float* __restrict__ Wci,
    float* __restrict__ q_out, float* __restrict__ erase_out,
    float* __restrict__ wh_out, float* __restrict__ wx_out)
{
    __shared__ float4 sh[2048];          // 32 KB
    __shared__ float red[8];
    int tid  = threadIdx.x;              // 0..511
    int lane = tid & 63;
    int wv   = tid >> 6;                 // 0..7
    int blk  = blockIdx.x;

    if (blk < HBLK) {
        const float4* h4 = (const float4*)h;
        #pragma unroll
        for (int k = 0; k < 4; ++k) sh[tid + 512 * k] = h4[tid + 512 * k];
        __syncthreads();

        int row  = blk * 4 + (wv >> 1);  // 0..6655
        int half = wv & 1;
        const float* W; float bias; float* out;
        row_target(row, Wq, bq, We, be, Wch, q_out, erase_out, wh_out, W, bias, out);

        const float4* W4  = (const float4*)W + half * 1024;
        const float4* shh = sh + half * 1024;

        float4 w[16];
        #pragma unroll
        for (int u = 0; u < 16; ++u) w[u] = W4[lane + 64 * u];
        float acc = 0.f;
        #pragma unroll
        for (int u = 0; u < 16; ++u) {
            float4 v = shh[lane + 64 * u];
            acc += w[u].x * v.x + w[u].y * v.y + w[u].z * v.z + w[u].w * v.w;
        }
        acc = waveReduceSum(acc);
        if (lane == 0) red[wv] = acc;
        __syncthreads();
        if (tid < 4) {
            int r2 = blk * 4 + tid;
            const float* W2; float b2; float* o2;
            row_target(r2, Wq, bq, We, be, Wch, q_out, erase_out, wh_out, W2, b2, o2);
            *o2 = red[2 * tid] + red[2 * tid + 1] + b2;
        }
    } else {
        // x-driven rows: 8 rows per block, wave-per-row
        const float4* x4 = (const float4*)x;
        if (tid < 256) sh[tid] = x4[tid];     // 4 KB of x
        __syncthreads();

        int row = (blk - HBLK) * 8 + wv;      // 0..2047
        const float4* W4 = (const float4*)(Wci + (size_t)row * 1024);
        float4 w[4];
        #pragma unroll
        for (int u = 0; u < 4; ++u) w[u] = W4[lane + 64 * u];
        float acc = 0.f;
        #pragma unroll
        for (int u = 0; u < 4; ++u) {
            float4 v = sh[lane + 64 * u];
            acc += w[u].x * v.x + w[u].y * v.y + w[u].z * v.z + w[u].w * v.w;
        }
        acc = waveReduceSum(acc);
        if (lane == 0) wx_out[row] = acc;
    }
}

// ---------------------------------------------------------------- K2: scalars + cdiff
// scal[0]=beta, scal[1]=gamma, scal[2]=q_norm, scal[3]=alpha
__global__ void k_scalars(const float* __restrict__ h, const float* __restrict__ x,
                          const float* __restrict__ us, const float* __restrict__ bs,
                          const float* __restrict__ ul, const float* __restrict__ bl,
                          const float* __restrict__ uca, const float* __restrict__ bca,
                          const float* __restrict__ q, const float* __restrict__ erase,
                          const float* __restrict__ wh, const float* __restrict__ wx,
                          float* __restrict__ scal, float* __restrict__ cdiff)
{
    __shared__ float red[16];
    __shared__ float sh_alpha;
    int tid = threadIdx.x, lane = tid & 63, wid = tid >> 6;

    float s_us = 0.f, s_ul = 0.f, s_a = 0.f, s_q2 = 0.f;
    for (int i = tid; i < 8192; i += 1024) {
        float hv = h[i];
        s_us += us[i] * hv;
        s_ul += ul[i] * hv;
        s_a  += uca[i] * hv;
    }
    { int i = tid; if (i < 1024) s_a += uca[8192 + i] * x[i]; }
    for (int i = tid; i < 2560; i += 1024) { float qv = q[i]; s_q2 += qv * qv; }

    float vals[4] = { s_us, s_ul, s_a, s_q2 };
    float res[4];
    #pragma unroll
    for (int k = 0; k < 4; ++k) {
        float v = waveReduceSum(vals[k]);
        __syncthreads();
        if (lane == 0) red[wid] = v;
        __syncthreads();
        float r = 0.f;
        if (tid == 0) { for (int i = 0; i < 16; ++i) r += red[i]; }
        res[k] = r;
    }

    if (tid == 0) {
        float z = res[0] + bs[0];
        float sp = (z > 20.f) ? z : log1pf(expf(z));
        float beta  = sp + 1.0f;
        float gamma = 1.f / (1.f + expf(-(res[1] + bl[0])));
        float alpha = res[2] + bca[0];
        float qn    = fmaxf(sqrtf(res[3]), EPS_F);
        scal[0] = beta; scal[1] = gamma; scal[2] = qn; scal[3] = alpha;
        sh_alpha = alpha;
    }
    __syncthreads();
    float alpha = sh_alpha;
    for (int j = tid; j < 2048; j += 1024) {
        float cand = fmaxf(wh[j] + alpha * wx[j], 0.f);
        cdiff[j] = cand - erase[j];
    }
}

// ---------------------------------------------------------------- K3: row pass (dots, norms, logits, new_ema)
__global__ void k_rowpass(const float* __restrict__ ma, const float* __restrict__ mc,
                          const float* __restrict__ q, const float* __restrict__ ema,
                          const float* __restrict__ scal,
                          float* __restrict__ logit, float* __restrict__ newema_out)
{
    int wave = (blockIdx.x * blockDim.x + threadIdx.x) >> 6;
    int lane = threadIdx.x & 63;
    if (wave >= N_LOC) return;
    int row = wave;

    const float4* a4 = (const float4*)(ma + (size_t)row * A_SIZE);
    const float4* c4 = (const float4*)(mc + (size_t)row * C_SIZE);
    const float4* q4 = (const float4*)q;

    float dot = 0.f, ssq = 0.f;
    #pragma unroll
    for (int i = lane; i < 128; i += 64) {           // address part: 512 floats
        float4 v = a4[i], qq = q4[i];
        dot += v.x*qq.x + v.y*qq.y + v.z*qq.z + v.w*qq.w;
        ssq += v.x*v.x + v.y*v.y + v.z*v.z + v.w*v.w;
    }
    #pragma unroll
    for (int i = lane; i < 512; i += 64) {           // contents part: 2048 floats
        float4 v = c4[i], qq = q4[128 + i];
        dot += v.x*qq.x + v.y*qq.y + v.z*qq.z + v.w*qq.w;
        ssq += v.x*v.x + v.y*v.y + v.z*v.z + v.w*v.w;
    }
    dot = waveReduceSum(dot);
    ssq = waveReduceSum(ssq);
    if (lane == 0) {
        float beta = scal[0], gamma = scal[1], qn = scal[2];
        float mn  = fmaxf(sqrtf(ssq), EPS_F);
        float sim = beta * dot / (mn * qn);
        float e   = ema[row];
        logit[row]      = sim - gamma * e;
        newema_out[row] = 0.1f * e + 0.9f * sim;
    }
}

// ---------------------------------------------------------------- K4: softmax over 8192 logits
__global__ void k_softmax(const float* __restrict__ logit, float* __restrict__ addr_out)
{
    __shared__ float red[16];
    __shared__ float s_max, s_sum;
    int tid = threadIdx.x, lane = tid & 63, wid = tid >> 6;

    float v[8];
    float lmax = -INFINITY;
    #pragma unroll
    for (int k = 0; k < 8; ++k) { v[k] = logit[tid + k * 1024]; lmax = fmaxf(lmax, v[k]); }
    lmax = waveReduceMax(lmax);
    if (lane == 0) red[wid] = lmax;
    __syncthreads();
    if (tid == 0) { float m = red[0]; for (int i = 1; i < 16; ++i) m = fmaxf(m, red[i]); s_max = m; }
    __syncthreads();
    float m = s_max, lsum = 0.f;
    #pragma unroll
    for (int k = 0; k < 8; ++k) { v[k] = expf(v[k] - m); lsum += v[k]; }
    lsum = waveReduceSum(lsum);
    __syncthreads();
    if (lane == 0) red[wid] = lsum;
    __syncthreads();
    if (tid == 0) { float s = 0.f; for (int i = 0; i < 16; ++i) s += red[i]; s_sum = s; }
    __syncthreads();
    float inv = 1.f / s_sum;
    #pragma unroll
    for (int k = 0; k < 8; ++k) addr_out[tid + k * 1024] = v[k] * inv;
}

// ---------------------------------------------------------------- K5: fused column pass (new_mem + read_vec partials)
// grid: (D_FULL/256, NCHUNK); each thread owns one full_mem column within one 64-row chunk
__global__ void k_colpass(const float* __restrict__ ma, const float* __restrict__ mc,
                          const float* __restrict__ addr, const float* __restrict__ cdiff,
                          float* __restrict__ newmem_out, float* __restrict__ rvpart)
{
    int c     = blockIdx.x * 256 + threadIdx.x;   // 0..2559
    int chunk = blockIdx.y;                       // 0..NCHUNK-1
    const int RPC = N_LOC / NCHUNK;               // 64
    int r0 = chunk * RPC, r1 = r0 + RPC;

    float acc = 0.f;
    if (c < A_SIZE) {
        const float* p = ma + c;
        for (int r = r0; r < r1; ++r) {
            float val = p[(size_t)r * A_SIZE];
            float a = addr[r];
            if (r != N_LOC - 1) acc += a * val;
        }
    } else {
        int cc = c - A_SIZE;
        float cd = cdiff[cc];
        const float* p = mc + cc;
        float* o = newmem_out + cc;
        for (int r = r0; r < r1; ++r) {
            float val = p[(size_t)r * C_SIZE];
            float a = addr[r];
            if (r != N_LOC - 1) acc += a * val;
            o[(size_t)r * C_SIZE] = val + a * cd;
        }
    }
    rvpart[(size_t)chunk * D_FULL + c] = acc;
}

// ---------------------------------------------------------------- K6: reduce read_vec partials
__global__ void k_rvreduce(const float* __restrict__ rvpart, float* __restrict__ rv_out)
{
    int c = blockIdx.x * 256 + threadIdx.x;
    if (c >= D_FULL) return;
    float s = 0.f;
    for (int k = 0; k < NCHUNK; ++k) s += rvpart[(size_t)k * D_FULL + c];
    rv_out[c] = s;
}

// ---------------------------------------------------------------- launch
extern "C" void kernel_launch(void* const* d_in, const int* in_sizes, int n_in,
                              void* d_out, int out_size, void* d_ws, size_t ws_size,
                              hipStream_t stream)
{
    const float* h   = (const float*)d_in[0];
    const float* x   = (const float*)d_in[1];
    const float* mc  = (const float*)d_in[2];
    const float* ma  = (const float*)d_in[3];
    const float* ema = (const float*)d_in[4];
    const float* Wq  = (const float*)d_in[5];
    const float* bq  = (const float*)d_in[6];
    const float* us  = (const float*)d_in[7];
    const float* bs  = (const float*)d_in[8];
    const float* ul  = (const float*)d_in[9];
    const float* bl  = (const float*)d_in[10];
    const float* We  = (const float*)d_in[11];
    const float* be  = (const float*)d_in[12];
    const float* Wch = (const float*)d_in[13];
    const float* Wci = (const float*)d_in[14];
    const float* uca = (const float*)d_in[15];
    const float* bca = (const float*)d_in[16];

    float* out = (float*)d_out;
    float* rv_out     = out;                              // 2560
    float* newmem_out = out + D_FULL;                     // 8192*2048
    float* addr_out   = newmem_out + (size_t)N_LOC * C_SIZE; // 8192
    float* newema_out = addr_out + N_LOC;                 // 8192

    float* ws = (float*)d_ws;
    float* w_query = ws;            // 2560
    float* w_erase = ws + 2560;     // 2048
    float* w_wh    = ws + 4608;     // 2048
    float* w_wx    = ws + 6656;     // 2048
    float* w_cdiff = ws + 8704;     // 2048
    float* w_scal  = ws + 10752;    // 8
    float* w_logit = ws + 10760;    // 8192
    float* w_rvp   = ws + 18952;    // NCHUNK*2560

    // K1: all mat-vecs (1664 h-blocks * 4 rows + 256 x-blocks * 8 rows)
    k_matvec<<<1920, 512, 0, stream>>>(h, x, Wq, bq, We, be, Wch, Wci,
                                       w_query, w_erase, w_wh, w_wx);
    // K2: scalars + cdiff
    k_scalars<<<1, 1024, 0, stream>>>(h, x, us, bs, ul, bl, uca, bca,
                                      w_query, w_erase, w_wh, w_wx, w_scal, w_cdiff);
    // K3: per-row dot/norm -> logit, new_ema
    k_rowpass<<<2048, 256, 0, stream>>>(ma, mc, w_query, ema, w_scal, w_logit, newema_out);
    // K4: softmax -> address
    k_softmax<<<1, 1024, 0, stream>>>(w_logit, addr_out);
    // K5: fused new_mem + read_vec partials
    dim3 g5(D_FULL / 256, NCHUNK);
    k_colpass<<<g5, 256, 0, stream>>>(ma, mc, addr_out, w_cdiff, newmem_out, w_rvp);
    // K6: reduce read_vec partials
    k_rvreduce<<<10, 256, 0, stream>>>(w_rvp, rv_out);
}